// Round 1
// baseline (77.645 us; speedup 1.0000x reference)
//
#include <hip/hip_runtime.h>
#include <math.h>

// Modulated deformable conv v2: B=4, C=256, H=W=64, O=256, K=3, PAD=1
// r19: K3 rewritten: (a) dwordx4 gathers (8 instead of 32 VMEM gather instrs
//      per thread-iter; TA address count /4), (b) double-buffered cols +
//      single producer-side (lgkmcnt-only) barrier per K-chunk with gather
//      prefetch one chunk ahead. K1 nhwcpack, K2 offmask_mfma verbatim.

constexpr int Bn = 4;
constexpr int Cn = 256;
constexpr int Hn = 64;
constexpr int Wn = 64;
constexpr int On = 256;
constexpr int PB = Hn * Wn;     // 4096
constexpr int NCH = 27;

typedef __attribute__((ext_vector_type(8))) short bf16x8;  // 8 bf16 (4 VGPRs)
typedef __attribute__((ext_vector_type(4))) float f32x4;
typedef __attribute__((ext_vector_type(4))) uint  uint4v;

union FragU { uint4 u; bf16x8 h; };

__device__ inline ushort f2bf(float f) {
    uint u = __builtin_bit_cast(uint, f);
    return (ushort)((u + 0x7fffu + ((u >> 16) & 1u)) >> 16);
}
__device__ inline float bf2f(ushort h) {
    uint u = (uint)h << 16;
    return __builtin_bit_cast(float, u);
}
__device__ inline float bflo(uint u) { u <<= 16;          return __builtin_bit_cast(float, u); }
__device__ inline float bfhi(uint u) { u &= 0xffff0000u;  return __builtin_bit_cast(float, u); }

// ---------------------------------------------------------------- kernel 1
// (r16/r17-proven) NCHW fp32 -> NHWC bf16 hi/lo planes + weight packing.
__global__ __launch_bounds__(256)
void nhwcpack_kernel(const float* __restrict__ x,
                     const float* __restrict__ w,
                     const float* __restrict__ offw,
                     const float* __restrict__ modw,
                     ushort* __restrict__ xbf, ushort* __restrict__ xlr,
                     ushort* __restrict__ wTb,
                     ushort* __restrict__ owh, ushort* __restrict__ owl)
{
    const int bid = blockIdx.x;
    const int b = bid >> 7, seg = bid & 127;
    const int t = threadIdx.x;
    __shared__ float tile[32][257];

    const float* src = x + (size_t)b * Cn * PB + seg * 32;
    #pragma unroll 4
    for (int i = 0; i < 32; ++i) {
        const int idx = i * 256 + t;
        const int c = idx >> 5, p = idx & 31;
        tile[p][c] = src[(size_t)c * PB + p];
    }
    __syncthreads();

    const int pr = t & 127;
    const int r0 = (t >> 7) * 16;
    uint* dH = reinterpret_cast<uint*>(xbf + ((size_t)b * PB + seg * 32) * 256);
    uint* dL = reinterpret_cast<uint*>(xlr + ((size_t)b * PB + seg * 32) * 256);
    #pragma unroll 4
    for (int i = 0; i < 16; ++i) {
        const int row = r0 + i;
        const float v0 = tile[row][2 * pr];
        const float v1 = tile[row][2 * pr + 1];
        const ushort h0 = f2bf(v0), h1 = f2bf(v1);
        const ushort l0 = f2bf(v0 - bf2f(h0));
        const ushort l1 = f2bf(v1 - bf2f(h1));
        dH[(size_t)row * 128 + pr] = (uint)h0 | ((uint)h1 << 16);
        dL[(size_t)row * 128 + pr] = (uint)l0 | ((uint)l1 << 16);
    }

    #pragma unroll 1
    for (int u = 0; u < 5; ++u) {
        int unit = (u < 4) ? bid * 4 + u : (bid < 256 ? 2048 + bid : -1);
        if (unit < 0) break;
        const int tap = unit >> 8, c = unit & 255;
        const int o = t;
        wTb[((size_t)(unit >> 3) * 256 + o) * 8 + (c & 7)] =
            f2bf(w[((size_t)o * Cn + c) * 9 + tap]);
        if (o < 32) {
            float v = 0.f;
            if (o < 18)      v = offw[((size_t)o * Cn + c) * 9 + tap];
            else if (o < 27) v = modw[((size_t)(o - 18) * Cn + c) * 9 + tap];
            const ushort h = f2bf(v);
            const ushort l = f2bf(v - bf2f(h));
            const size_t base = ((size_t)(unit >> 3) * 32 + o) * 8 + (c & 7);
            owh[base] = h;
            owl[base] = l;
        }
    }
}

// ---------------------------------------------------------------- kernel 2
// (r13-proven, verbatim) offset/mask conv via split-bf16 MFMA -> offm global.
__global__ __launch_bounds__(512, 2)
void offmask_mfma_kernel(const ushort* __restrict__ xbf,
                         const ushort* __restrict__ xlr,
                         const float* __restrict__ offb,
                         const float* __restrict__ modb,
                         const ushort* __restrict__ owh,
                         const ushort* __restrict__ owl,
                         float* __restrict__ offm)
{
    const int hw = blockIdx.x;
    const int blk = (hw & 7) * 32 + (hw >> 3);
    const int b = blk >> 6, row = blk & 63;
    const int t = threadIdx.x;
    const int lane = t & 63;
    const int wv  = t >> 6;
    const int l15 = lane & 15;
    const int g   = lane >> 4;
    const int mt  = wv >> 2;
    const int nt  = wv & 3;

    __shared__ uint colsH[8][1024];
    __shared__ uint colsL[8][1024];

    const ushort* xhb = xbf + (size_t)b * PB * 256;
    const ushort* xlb = xlr + (size_t)b * PB * 256;
    const int posT0 = t >> 4;
    const int chq   = t & 15;

    const int ws0 = posT0 * 16
        + 4 * ((chq >> 2) ^ (posT0 & 3) ^ ((posT0 >> 2) & 3)) + (chq & 3);
    const int posT1 = posT0 + 32;
    const int ws1 = posT1 * 16
        + 4 * ((chq >> 2) ^ (posT1 & 3) ^ ((posT1 >> 2) & 3)) + (chq & 3);

    const uint4* owhV = reinterpret_cast<const uint4*>(owh);
    const uint4* owlV = reinterpret_cast<const uint4*>(owl);

    f32x4 acc = (f32x4){0.f, 0.f, 0.f, 0.f};
    const int p = nt * 16 + l15;
    const int ridx = p * 4 + (g ^ (p & 3) ^ ((p >> 2) & 3));

    #pragma unroll 1
    for (int tap = 0; tap < 9; ++tap) {
        const int ty = tap / 3, tx = tap % 3;
        const int y = row - 1 + ty;
        const int xc0 = posT0 - 1 + tx;
        const int xc1 = posT1 - 1 + tx;
        const bool ok0 = (y >= 0) && (y < Hn) && (xc0 >= 0) && (xc0 < Wn);
        const bool ok1 = (y >= 0) && (y < Hn) && (xc1 >= 0) && (xc1 < Wn);
        const int ya  = max(y, 0);
        const int xa0 = min(max(xc0, 0), Wn - 1);
        const int xa1 = min(max(xc1, 0), Wn - 1);
        const size_t p0b = ((size_t)(ya * Wn + xa0)) * 256 + 2 * chq;
        const size_t p1b = ((size_t)(ya * Wn + xa1)) * 256 + 2 * chq;

        uint h0[8], l0[8], h1[8], l1[8];
        #pragma unroll
        for (int s = 0; s < 8; ++s) {
            h0[s] = l0[s] = h1[s] = l1[s] = 0u;
            if (ok0) {
                h0[s] = *reinterpret_cast<const uint*>(xhb + p0b + s * 32);
                l0[s] = *reinterpret_cast<const uint*>(xlb + p0b + s * 32);
            }
            if (ok1) {
                h1[s] = *reinterpret_cast<const uint*>(xhb + p1b + s * 32);
                l1[s] = *reinterpret_cast<const uint*>(xlb + p1b + s * 32);
            }
        }
        uint4 aH[8], aL[8];
        #pragma unroll
        for (int s = 0; s < 8; ++s) {
            const size_t kb = (size_t)((tap * 8 + s) * 4 + g) * 32 + mt * 16 + l15;
            aH[s] = owhV[kb];
            aL[s] = owlV[kb];
        }

        __syncthreads();

        #pragma unroll
        for (int s = 0; s < 8; ++s) {
            colsH[s][ws0] = h0[s];
            colsL[s][ws0] = l0[s];
            colsH[s][ws1] = h1[s];
            colsL[s][ws1] = l1[s];
        }
        __syncthreads();

        #pragma unroll
        for (int s = 0; s < 8; ++s) {
            FragU aHH, aLL, bH, bL;
            aHH.u = aH[s]; aLL.u = aL[s];
            bH.u = reinterpret_cast<const uint4*>(colsH[s])[ridx];
            bL.u = reinterpret_cast<const uint4*>(colsL[s])[ridx];
            acc = __builtin_amdgcn_mfma_f32_16x16x32_bf16(aHH.h, bH.h, acc, 0, 0, 0);
            acc = __builtin_amdgcn_mfma_f32_16x16x32_bf16(aHH.h, bL.h, acc, 0, 0, 0);
            acc = __builtin_amdgcn_mfma_f32_16x16x32_bf16(aLL.h, bH.h, acc, 0, 0, 0);
        }
    }

    const int pos = nt * 16 + l15;
    #pragma unroll
    for (int j = 0; j < 4; ++j) {
        const int ch = mt * 16 + g * 4 + j;
        if (ch < NCH) {
            float v = acc[j];
            if (ch < 18) v += offb[ch];
            else         v = 2.f / (1.f + expf(-(v + modb[ch - 18])));
            offm[((size_t)(b * NCH + ch)) * PB + row * 64 + pos] = v;
        }
    }
}

// ---------------------------------------------------------------- kernel 3
// r19 rewrite. grid: 256 = (b,row) XCD-swizzled. 512 threads = 8 waves;
// wave = M 32 x N 64. Per K-chunk (cch = 128 ch): each thread gathers
// 8x dwordx4 (2 pos x 4 corners, 8 channels each), combines bilinear+mask
// in fp32, writes ONE swizzled uint4 per pos into double-buffered cols,
// lgkmcnt-only barrier, MFMA. Gathers for chunk cch+1 issued before the
// combine of chunk cch (latency hidden; no vmcnt(0) drain at barriers).
__global__ __launch_bounds__(512, 2)
void deform_nhwc_kernel(const ushort* __restrict__ xbf,
                        const float* __restrict__ offm,
                        const ushort* __restrict__ wTb,
                        float* __restrict__ out)
{
    const int hw = blockIdx.x;
    const int blk = (hw & 7) * 32 + (hw >> 3);   // XCD swizzle (256 = 8*32)
    const int b = blk >> 6, row = blk & 63;
    const int p0 = row * 64;
    const int t = threadIdx.x;
    const int lane = t & 63;
    const int wv  = t >> 6;
    const int l15 = lane & 15;
    const int g   = lane >> 4;

    __shared__ int4   s_off[576];        // [tap][pos 0..63]
    __shared__ float4 s_wgt[576];
    __shared__ uint   cols[2][4][1024];  // double-buffered (32 KB)

    for (int ti = t; ti < 576; ti += 512) {
        const int k = ti >> 6, pos = ti & 63;
        const int p = p0 + pos;
        const float dy = offm[((size_t)(b * NCH + 2 * k)) * PB + p];
        const float dx = offm[((size_t)(b * NCH + 2 * k + 1)) * PB + p];
        const float m  = offm[((size_t)(b * NCH + 18 + k)) * PB + p];
        const int ky = k / 3, kx = k % 3;
        const float py = dy + (float)(ky + row - 1);
        const float px = dx + (float)(kx + pos - 1);
        const float y0f = floorf(py), x0f = floorf(px);
        const float fy = py - y0f, fx = px - x0f;
        const int y0 = (int)y0f, x0i = (int)x0f;
        const int y1 = y0 + 1, x1 = x0i + 1;
        const bool vy0 = (y0 >= 0) && (y0 < Hn);
        const bool vy1 = (y1 >= 0) && (y1 < Hn);
        const bool vx0 = (x0i >= 0) && (x0i < Wn);
        const bool vx1 = (x1 >= 0) && (x1 < Wn);
        const int y0c = min(max(y0, 0), Hn - 1);
        const int y1c = min(max(y1, 0), Hn - 1);
        const int x0c = min(max(x0i, 0), Wn - 1);
        const int x1c = min(max(x1, 0), Wn - 1);
        s_off[ti] = make_int4(y0c * Wn + x0c, y0c * Wn + x1c,
                              y1c * Wn + x0c, y1c * Wn + x1c);
        s_wgt[ti] = make_float4(
            (vy0 && vx0) ? (1.f - fy) * (1.f - fx) * m : 0.f,
            (vy0 && vx1) ? (1.f - fy) * fx * m : 0.f,
            (vy1 && vx0) ? fy * (1.f - fx) * m : 0.f,
            (vy1 && vx1) ? fy * fx * m : 0.f);
    }
    __syncthreads();   // tap tables visible before ANY gather

    const ushort* xb = xbf + (size_t)b * PB * 256;
    const int posT = t >> 4;       // 0..31; this thread stages posT and posT+32
    const int chq  = t & 15;
    const uint4* wvp = reinterpret_cast<const uint4*>(wTb);
    const int o0 = wv * 32;

    // this thread owns channels 8*chq..8*chq+7 of each 128-ch chunk:
    //   K-step s = chq>>2, channel pairs 4*(chq&3)+j (j=0..3) within s.
    // Swizzle slot = 4*((pair>>2)^P)+(pair&3) with P pos-dependent -> the
    // 4 pairs land in ONE contiguous uint4 slot: index posT*4 + grp.
    const int sIdx = chq >> 2;
    const int grp  = (chq & 3) ^ (posT & 3) ^ ((posT >> 2) & 3);
    const int w4a  = posT * 4 + grp;           // posB slot = w4a + 128

    int ri[4];
    #pragma unroll
    for (int nt = 0; nt < 4; ++nt) {
        const int p = nt * 16 + l15;
        ri[nt] = p * 4 + (g ^ (p & 3) ^ ((p >> 2) & 3));
    }

    f32x4 acc[2][4];
    #pragma unroll
    for (int ot = 0; ot < 2; ++ot)
        #pragma unroll
        for (int nt = 0; nt < 4; ++nt)
            acc[ot][nt] = (f32x4){0.f, 0.f, 0.f, 0.f};

    const ushort* xq = xb + 8 * chq;   // 16B-aligned per-thread channel base

    auto ISSUE = [&](int cch, uint4v (&q)[2][4], float4& wA, float4& wB) {
        const int tap = cch >> 1;
        const ushort* xcc = xq + (cch & 1) * 128;
        const int4 oA = s_off[tap * 64 + posT];
        const int4 oB = s_off[tap * 64 + posT + 32];
        wA = s_wgt[tap * 64 + posT];
        wB = s_wgt[tap * 64 + posT + 32];
        q[0][0] = *reinterpret_cast<const uint4v*>(xcc + (size_t)oA.x * 256);
        q[0][1] = *reinterpret_cast<const uint4v*>(xcc + (size_t)oA.y * 256);
        q[0][2] = *reinterpret_cast<const uint4v*>(xcc + (size_t)oA.z * 256);
        q[0][3] = *reinterpret_cast<const uint4v*>(xcc + (size_t)oA.w * 256);
        q[1][0] = *reinterpret_cast<const uint4v*>(xcc + (size_t)oB.x * 256);
        q[1][1] = *reinterpret_cast<const uint4v*>(xcc + (size_t)oB.y * 256);
        q[1][2] = *reinterpret_cast<const uint4v*>(xcc + (size_t)oB.z * 256);
        q[1][3] = *reinterpret_cast<const uint4v*>(xcc + (size_t)oB.w * 256);
    };

    auto LOADA = [&](int cch, uint4 (&apre)[4][2]) {
        #pragma unroll
        for (int s = 0; s < 4; ++s) {
            const int kb = (cch * 4 + s) * 4 + g;
            apre[s][0] = wvp[(size_t)kb * 256 + o0 + l15];
            apre[s][1] = wvp[(size_t)kb * 256 + o0 + 16 + l15];
        }
    };

    auto COMBINE = [&](const uint4v (&q)[2][4], const float4& wA,
                       const float4& wB, uint* cbuf) {
        uint pa[4], pb[4];
        #pragma unroll
        for (int j = 0; j < 4; ++j) {
            const uint ca = q[0][0][j], cb = q[0][1][j];
            const uint cc = q[0][2][j], cd = q[0][3][j];
            const float v0 = wA.x * bflo(ca) + wA.y * bflo(cb)
                           + wA.z * bflo(cc) + wA.w * bflo(cd);
            const float v1 = wA.x * bfhi(ca) + wA.y * bfhi(cb)
                           + wA.z * bfhi(cc) + wA.w * bfhi(cd);
            pa[j] = (uint)f2bf(v0) | ((uint)f2bf(v1) << 16);
            const uint ce = q[1][0][j], cf = q[1][1][j];
            const uint cg = q[1][2][j], ch = q[1][3][j];
            const float u0 = wB.x * bflo(ce) + wB.y * bflo(cf)
                           + wB.z * bflo(cg) + wB.w * bflo(ch);
            const float u1 = wB.x * bfhi(ce) + wB.y * bfhi(cf)
                           + wB.z * bfhi(cg) + wB.w * bfhi(ch);
            pb[j] = (uint)f2bf(u0) | ((uint)f2bf(u1) << 16);
        }
        uint4v* dst = reinterpret_cast<uint4v*>(cbuf + sIdx * 1024);
        dst[w4a]       = (uint4v){pa[0], pa[1], pa[2], pa[3]};
        dst[w4a + 128] = (uint4v){pb[0], pb[1], pb[2], pb[3]};
    };

    auto MFMAS = [&](const uint* cbuf, const uint4 (&apre)[4][2]) {
        #pragma unroll
        for (int s = 0; s < 4; ++s) {
            FragU a0, a1, bf4[4];
            a0.u = apre[s][0]; a1.u = apre[s][1];
            #pragma unroll
            for (int nt = 0; nt < 4; ++nt)
                bf4[nt].u = reinterpret_cast<const uint4*>(cbuf + s * 1024)[ri[nt]];
            #pragma unroll
            for (int nt = 0; nt < 4; ++nt) {
                acc[0][nt] = __builtin_amdgcn_mfma_f32_16x16x32_bf16(
                    a0.h, bf4[nt].h, acc[0][nt], 0, 0, 0);
                acc[1][nt] = __builtin_amdgcn_mfma_f32_16x16x32_bf16(
                    a1.h, bf4[nt].h, acc[1][nt], 0, 0, 0);
            }
        }
    };

    uint4v qA[2][4], qB[2][4];
    uint4  apre[4][2];
    float4 wA0, wB0, wA1, wB1;

    ISSUE(0, qA, wA0, wB0);
    #pragma unroll 1
    for (int jj = 0; jj < 9; ++jj) {
        // even phase: cch = 2*jj, data in qA, buffer 0
        ISSUE(2 * jj + 1, qB, wA1, wB1);     // prefetch next chunk's gathers
        LOADA(2 * jj, apre);
        COMBINE(qA, wA0, wB0, &cols[0][0][0]);
        asm volatile("s_waitcnt lgkmcnt(0)" ::: "memory");  // my LDS writes done
        __builtin_amdgcn_s_barrier();                        // vmcnt rides across
        asm volatile("" ::: "memory");
        MFMAS(&cols[0][0][0], apre);

        // odd phase: cch = 2*jj+1, data in qB, buffer 1
        if (jj < 8) ISSUE(2 * jj + 2, qA, wA0, wB0);
        LOADA(2 * jj + 1, apre);
        COMBINE(qB, wA1, wB1, &cols[1][0][0]);
        asm volatile("s_waitcnt lgkmcnt(0)" ::: "memory");
        __builtin_amdgcn_s_barrier();
        asm volatile("" ::: "memory");
        MFMAS(&cols[1][0][0], apre);
    }

    float* ob = out + (size_t)b * On * PB;
    #pragma unroll
    for (int ot = 0; ot < 2; ++ot)
        #pragma unroll
        for (int nt = 0; nt < 4; ++nt)
            #pragma unroll
            for (int j = 0; j < 4; ++j)
                ob[((size_t)(o0 + ot * 16 + g * 4 + j)) * PB
                   + p0 + nt * 16 + l15] = acc[ot][nt][j];
}

// ---------------------------------------------------------------- launch
extern "C" void kernel_launch(void* const* d_in, const int* in_sizes, int n_in,
                              void* d_out, int out_size, void* d_ws, size_t ws_size,
                              hipStream_t stream)
{
    const float* x    = (const float*)d_in[0];
    const float* offw = (const float*)d_in[1];
    const float* offb = (const float*)d_in[2];
    const float* modw = (const float*)d_in[3];
    const float* modb = (const float*)d_in[4];
    const float* wgt  = (const float*)d_in[5];
    float* out = (float*)d_out;

    char* ws = (char*)d_ws;
    float*  offm = (float*)ws;                   // 1,769,472 B
    ushort* wTb  = (ushort*)(ws + 1769472);      // 1,179,648 B
    ushort* owh  = (ushort*)(ws + 2949120);      // 147,456 B
    ushort* owl  = (ushort*)(ws + 3096576);      // 147,456 B
    ushort* xbf  = (ushort*)(ws + 3244032);      // 8,388,608 B
    ushort* xlr  = (ushort*)(ws + 11632640);     // 8,388,608 B -> 20.0 MB total

    nhwcpack_kernel<<<dim3(512), dim3(256), 0, stream>>>(
        x, wgt, offw, modw, xbf, xlr, wTb, owh, owl);
    offmask_mfma_kernel<<<dim3(256), dim3(512), 0, stream>>>(
        xbf, xlr, offb, modb, owh, owl, offm);
    deform_nhwc_kernel<<<dim3(256), dim3(512), 0, stream>>>(
        xbf, offm, wTb, out);
}